// Round 1
// 472.119 us; speedup vs baseline: 1.1920x; 1.1920x over previous
//
#include <hip/hip_runtime.h>

#define NN     3072
#define INDIM  128
#define NH     4
#define DD     64
#define CC     256   // NH*DD
#define EE     8
#define NODE_T 8
#define TI16   16    // i-rows per block in gat_fused (dense MFMA M=16)
#define BJ     64    // j-tile width
#define JSPLIT 4     // j-range split across blocks (partial sums)
#define JRANGE (NN / JSPLIT)   // 768
#define NTS    (JRANGE / BJ)   // 12 tiles per block
#define PTJ    72    // padded j stride in shorts (144 B rows, 16B-aligned)
#define NCH    (NN / 32)       // 96 B-fragment chunks along j

typedef short short8v __attribute__((ext_vector_type(8)));
typedef unsigned short ushort8v __attribute__((ext_vector_type(8)));
typedef float float4v __attribute__((ext_vector_type(4)));

__device__ __forceinline__ float bf2f(unsigned short u) {
    return __uint_as_float(((unsigned int)u) << 16);
}
__device__ __forceinline__ unsigned short f2bf(float f) {
    unsigned int u = __float_as_uint(f);
    u += 0x7fffu + ((u >> 16) & 1u);   // round-to-nearest-even
    return (unsigned short)(u >> 16);
}
__device__ __forceinline__ float rfl(float f) {   // force wave-uniform value to SGPR
    return __int_as_float(__builtin_amdgcn_readfirstlane(__float_as_int(f)));
}

// ---------------------------------------------------------------------------
// Kernel 1: h = x @ W. 8 nodes per block; thread owns channel c=tid.
// Writes htf in MFMA-B-FRAGMENT order: for chunk (32 j) of (head,f):
//   lane l = q*16+l15 holds Ht[d=f*16+l15][j=chunk*32+q*8 .. +8] contiguous.
// A thread here owns d=c&63 for 8 consecutive j (n0..n0+7) -> one ushort8v
// store lands exactly on its fragment slot. Makes gat_fused B-loads
// perfectly lane-contiguous dwordx4 (8 lines/instr vs ~16-32 before).
// ---------------------------------------------------------------------------
__global__ __launch_bounds__(256) void hproj(
    const float* __restrict__ x,      // (N,128)
    const float* __restrict__ W,      // (128,256)
    const float* __restrict__ a_src,  // (4,64)
    const float* __restrict__ a_dst,  // (4,64)
    unsigned short* __restrict__ htf, // ws: fragment-order bf16 (N*CC)
    float* __restrict__ s_src,        // ws: (N,4)
    float* __restrict__ s_dst)        // ws: (N,4)
{
    const int tid = threadIdx.x;
    const int n0  = blockIdx.x * NODE_T;
    const int h   = tid >> 6, lane = tid & 63;

    float acc[NODE_T] = {};
#pragma unroll 4
    for (int k = 0; k < INDIM; ++k) {
        const float wv = W[(size_t)k * CC + tid];
#pragma unroll
        for (int n = 0; n < NODE_T; ++n)
            acc[n] = fmaf(x[(size_t)(n0 + n) * INDIM + k], wv, acc[n]);
    }

    ushort8v hv;
#pragma unroll
    for (int n = 0; n < NODE_T; ++n) hv[n] = f2bf(acc[n]);
    // d = lane (since tid = h*64 + lane); f = lane>>4, l15 = lane&15
    unsigned short* dst = htf
        + (size_t)((h * 4 + (lane >> 4)) * NCH + (n0 >> 5)) * 512
        + (size_t)((((n0 >> 3) & 3) * 16 + (lane & 15)) * 8);
    *reinterpret_cast<ushort8v*>(dst) = hv;

    const float asv = a_src[h * DD + lane];
    const float adv = a_dst[h * DD + lane];
#pragma unroll
    for (int n = 0; n < NODE_T; ++n) {
        float s1 = acc[n] * asv, s2 = acc[n] * adv;
#pragma unroll
        for (int off = 32; off > 0; off >>= 1) {
            s1 += __shfl_xor(s1, off, 64);
            s2 += __shfl_xor(s2, off, 64);
        }
        if (lane == 0) {
            s_src[(size_t)(n0 + n) * NH + h] = s1;
            s_dst[(size_t)(n0 + n) * NH + h] = s2;
        }
    }
}

// ---------------------------------------------------------------------------
// Kernel 2 (fused, partial): 16-row i-tile, 1/4 of the j-range per block.
// Score phase: wave rw owns rows rw*4..rw*4+3; lane owns ONE j -> all loads
// (ef, adj, s_dst) fully coalesced; 40 prefetch VGPRs held across MFMA.
// MFMA phase: wave = head; A = p-tile (LDS, all 16 rows valid), B = htf
// fragment-order (lane-contiguous dwordx4, L2-resident).
// B-loads issued BEFORE ef prefetch so the in-order vmcnt wait for B does
// not drain the HBM prefetch (pinned with sched_barrier).
// Emits partial out/l sums; gat_ln merges + normalizes + LayerNorms.
// ---------------------------------------------------------------------------
__global__ __launch_bounds__(256, 3) void gat_fused(
    const int* __restrict__ adj,       // (N,N)
    const float* __restrict__ ef,      // (N,N,8)
    const unsigned short* __restrict__ htf,
    const float* __restrict__ s_src,   // (N,4)
    const float* __restrict__ s_dst,   // (N,4)
    const float* __restrict__ ep_w,    // (8,4)
    const float* __restrict__ ep_b,    // (4,)
    float* __restrict__ out_part,      // ws: (JSPLIT,N,256)
    float* __restrict__ l_part)        // ws: (JSPLIT,N,4)
{
    __shared__ unsigned short pt[2][NH][16][PTJ];   // 18.4 KB, dbuf

    const int tid  = threadIdx.x;
    const int rw   = tid >> 6;        // wave: row-group (score) / head (MFMA)
    const int lane = tid & 63;
    const int l15  = lane & 15;
    const int q    = lane >> 4;
    const int bid  = blockIdx.x;
    const int s    = bid & (JSPLIT - 1);
    const int i0   = (bid >> 2) * TI16;
    const int jb0  = s * JRANGE;

    // ---- constants ----
    float epw[EE][NH], epb4[NH];
#pragma unroll
    for (int e = 0; e < EE; ++e)
#pragma unroll
        for (int h = 0; h < NH; ++h) epw[e][h] = ep_w[e * NH + h];
#pragma unroll
    for (int h = 0; h < NH; ++h) epb4[h] = ep_b[h];
    float ssrc[4][4];   // wave-uniform -> SGPR
#pragma unroll
    for (int r = 0; r < 4; ++r)
#pragma unroll
        for (int h = 0; h < NH; ++h)
            ssrc[r][h] = rfl(s_src[(size_t)(i0 + rw * 4 + r) * NH + h]);

    float4v acc[4];
#pragma unroll
    for (int f = 0; f < 4; ++f) acc[f] = (float4v){0.f, 0.f, 0.f, 0.f};
    float l_loc[4][4] = {};

    // prefetch registers (one j per lane, 4 rows)
    float4 efA[4], efB[4], sd4;
    int    ajr[4];

#define LOADP(JN) {                                                          \
        const int jj = (JN) + lane;                                          \
        sd4 = *reinterpret_cast<const float4*>(s_dst + (size_t)jj * NH);     \
        _Pragma("unroll")                                                    \
        for (int r = 0; r < 4; ++r) {                                        \
            const size_t ro = (size_t)(i0 + rw * 4 + r) * NN;                \
            ajr[r] = adj[ro + jj];                                           \
            const float* ep = ef + (ro + jj) * EE;                           \
            efA[r] = *reinterpret_cast<const float4*>(ep);                   \
            efB[r] = *reinterpret_cast<const float4*>(ep + 4);               \
        } }

#define SCOREP(NB) {                                                         \
        const float sdh[4] = {sd4.x, sd4.y, sd4.z, sd4.w};                   \
        _Pragma("unroll")                                                    \
        for (int r = 0; r < 4; ++r) {                                        \
            const float ev[EE] = {efA[r].x, efA[r].y, efA[r].z, efA[r].w,    \
                                  efB[r].x, efB[r].y, efB[r].z, efB[r].w};   \
            _Pragma("unroll")                                                \
            for (int h = 0; h < NH; ++h) {                                   \
                float sc = ssrc[r][h] + sdh[h] + epb4[h];                    \
                _Pragma("unroll")                                            \
                for (int e = 0; e < EE; ++e)                                 \
                    sc = fmaf(ev[e], epw[e][h], sc);                         \
                sc = (sc > 0.f) ? sc : 0.2f * sc;                            \
                const float p = (ajr[r] == 0) ? 0.f : __expf(sc);            \
                const unsigned short bb = f2bf(p);                           \
                l_loc[r][h] += bf2f(bb);                                     \
                pt[NB][h][rw * 4 + r][lane] = bb;                            \
            } } }

    // ---- prologue: score tile 0 into pt[0] ----
    LOADP(jb0);
    SCOREP(0);
    __syncthreads();

    // ---- main loop ----
    int buf = 0;
    for (int t = 0; t < NTS; ++t) {
        const int jb   = jb0 + t * BJ;
        const int cid0 = jb >> 5;            // 2 chunks of 32 j per tile
        const bool pf  = (t + 1 < NTS);

        // 1) B fragments for tile t (issued FIRST so their vmcnt wait
        //    leaves the ef prefetch outstanding)
        short8v bfrag[2][4];
#pragma unroll
        for (int ks = 0; ks < 2; ++ks)
#pragma unroll
            for (int f = 0; f < 4; ++f)
                bfrag[ks][f] = *reinterpret_cast<const short8v*>(
                    htf + (size_t)((rw * 4 + f) * NCH + cid0 + ks) * 512 + lane * 8);
        __builtin_amdgcn_sched_barrier(0);

        // 2) prefetch next tile's globals (HBM, in flight through MFMA)
        if (pf) LOADP(jb + BJ);
        __builtin_amdgcn_sched_barrier(0);

        // 3) MFMA tile t: wave rw = head rw; all 16 M-rows valid
#pragma unroll
        for (int ks = 0; ks < 2; ++ks) {
            const short8v a = *reinterpret_cast<const short8v*>(
                &pt[buf][rw][l15][ks * 32 + q * 8]);
#pragma unroll
            for (int f = 0; f < 4; ++f)
                acc[f] = __builtin_amdgcn_mfma_f32_16x16x32_bf16(a, bfrag[ks][f], acc[f], 0, 0, 0);
        }

        // 4) score tile t+1 into the other buffer
        if (pf) SCOREP(buf ^ 1);
        __syncthreads();
        buf ^= 1;
    }

    // ---- l partial: wave rw owns rows rw*4..+3 (lanes held disjoint j) ----
#pragma unroll
    for (int r = 0; r < 4; ++r)
#pragma unroll
        for (int h = 0; h < NH; ++h) {
            float v = l_loc[r][h];
#pragma unroll
            for (int off = 32; off > 0; off >>= 1) v += __shfl_xor(v, off, 64);
            if (lane == 0)
                l_part[((size_t)s * NN + i0 + rw * 4 + r) * NH + h] = v;
        }

    // ---- out partial: wave rw = head rw; C row = q*4+reg, col = l15 ----
#pragma unroll
    for (int f = 0; f < 4; ++f)
#pragma unroll
        for (int rg = 0; rg < 4; ++rg)
            out_part[((size_t)s * NN + i0 + q * 4 + rg) * CC + rw * DD + f * 16 + l15] = acc[f][rg];
#undef LOADP
#undef SCOREP
}

// ---------------------------------------------------------------------------
// Kernel 3: merge JSPLIT partials, normalize by l, fused LayerNorm.
// Wave w handles row i0+w; lane owns channels {k*64+lane}.
// ---------------------------------------------------------------------------
__global__ __launch_bounds__(256) void gat_ln(
    const float* __restrict__ out_part,  // (JSPLIT,N,256)
    const float* __restrict__ l_part,    // (JSPLIT,N,4)
    const float* __restrict__ gamma,
    const float* __restrict__ beta,
    float* __restrict__ out)             // (N,256)
{
    const int tid = threadIdx.x, w = tid >> 6, lane = tid & 63;
    const int i = blockIdx.x * 4 + w;

    float v[4];
#pragma unroll
    for (int k = 0; k < 4; ++k) {
        float a = 0.f;
#pragma unroll
        for (int sp = 0; sp < JSPLIT; ++sp)
            a += out_part[((size_t)sp * NN + i) * CC + k * 64 + lane];
        float lb = 0.f;
#pragma unroll
        for (int sp = 0; sp < JSPLIT; ++sp)
            lb += l_part[((size_t)sp * NN + i) * NH + k];   // head of k*64+lane is k
        v[k] = a / lb;
    }

    float s1 = v[0] + v[1] + v[2] + v[3];
    float s2 = v[0] * v[0] + v[1] * v[1] + v[2] * v[2] + v[3] * v[3];
#pragma unroll
    for (int off = 32; off > 0; off >>= 1) {
        s1 += __shfl_xor(s1, off, 64);
        s2 += __shfl_xor(s2, off, 64);
    }
    const float mean = s1 * (1.f / CC);
    const float var  = s2 * (1.f / CC) - mean * mean;
    const float rstd = rsqrtf(var + 1e-5f);
    float* op = out + (size_t)i * CC;
#pragma unroll
    for (int k = 0; k < 4; ++k) {
        const int c = k * 64 + lane;
        op[c] = (v[k] - mean) * rstd * gamma[c] + beta[c];
    }
}

extern "C" void kernel_launch(void* const* d_in, const int* in_sizes, int n_in,
                              void* d_out, int out_size, void* d_ws, size_t ws_size,
                              hipStream_t stream) {
    const float* x     = (const float*)d_in[0];
    const int*   adj   = (const int*)d_in[1];
    const float* ef    = (const float*)d_in[2];
    const float* W     = (const float*)d_in[3];
    const float* a_src = (const float*)d_in[4];
    const float* a_dst = (const float*)d_in[5];
    const float* ep_w  = (const float*)d_in[6];
    const float* ep_b  = (const float*)d_in[7];
    const float* gamma = (const float*)d_in[8];
    const float* beta  = (const float*)d_in[9];

    // ws layout (14.45 MB total):
    //   s_src 48K | s_dst 48K | htf 1.5M bf16 | out_part 12.6M | l_part 192K
    float* s_src = (float*)d_ws;
    float* s_dst = s_src + (size_t)NN * NH;
    unsigned short* htf = (unsigned short*)(s_dst + (size_t)NN * NH);
    float* out_part = (float*)(htf + (size_t)NN * CC);
    float* l_part   = out_part + (size_t)JSPLIT * NN * CC;
    (void)ws_size; (void)in_sizes; (void)n_in; (void)out_size;

    hipLaunchKernelGGL(hproj, dim3(NN / NODE_T), dim3(256), 0, stream,
                       x, W, a_src, a_dst, htf, s_src, s_dst);
    hipLaunchKernelGGL(gat_fused, dim3((NN / TI16) * JSPLIT), dim3(256), 0, stream,
                       adj, ef, htf, s_src, s_dst, ep_w, ep_b, out_part, l_part);
    hipLaunchKernelGGL(gat_ln, dim3(NN / 4), dim3(256), 0, stream,
                       out_part, l_part, gamma, beta, (float*)d_out);
}